// Round 4
// baseline (475.630 us; speedup 1.0000x reference)
//
#include <hip/hip_runtime.h>
#include <stdint.h>

#define B 64
#define H 384
#define W 512
#define NPX (H*W)            // 196608
#define TRIM_IDX 157286      // int(0.8 * 196608)

#define NB1 2048             // stage1/2 bins (11 bits)
#define NB3 1024             // stage3 bins (10 bits)

// ---- workspace layout (uint32 units) ----
#define HIST_OFF 0
#define HIST_U32 (2*B*NB1)               // 262144 u32 = 1 MB
#define ACC_OFF  (HIST_OFF + HIST_U32)
#define N_OFF    (ACC_OFF + 0)           // [B]  u32 mask count (targ>0)
#define MS_OFF   (ACC_OFF + 64)          // [3][B] u32 subsample mask counts
#define TS_OFF   (ACC_OFF + 256)         // [B]  f32 tmae sum
#define GS_OFF   (ACC_OFF + 320)         // [4][B] f32 grad sums
#define TSUM_OFF (ACC_OFF + 576)         // [2][B] f32 total masked value sum
#define SB_OFF   (ACC_OFF + 704)         // [2][B] f32 sum of masked values < med
#define ZERO_U32 (HIST_U32 + 832)        // zero [0, ZERO_U32) at launch
// persistent (written before read each launch, not zeroed)
#define K_OFF    (ACC_OFF + 832)         // [2][B] u32 remaining rank
#define PFX_OFF  (ACC_OFF + 960)         // [2][B] u32 selected bit prefix
#define EQ_OFF   (ACC_OFF + 1088)        // [2][B] u32 count equal to median
#define SH_OFF   (ACC_OFF + 1216)        // [2][B] f32 median (shift)
#define RS_OFF   (ACC_OFF + 1344)        // [2][B] f32 reciprocal scale
#define THR_OFF  (ACC_OFF + 1472)        // [B]  f32 trim threshold
#define C2_OFF   (ACC_OFF + 1536)        // [B]  u32 count targ>shift_t

__device__ __forceinline__ uint32_t fmap(float f) {
    uint32_t b = __float_as_uint(f);
    return (b & 0x80000000u) ? ~b : (b | 0x80000000u);
}
__device__ __forceinline__ float funmap(uint32_t u) {
    uint32_t b = (u & 0x80000000u) ? (u & 0x7fffffffu) : ~u;
    return __uint_as_float(b);
}

// ---------------- stage 1: 11-bit histogram + n + total sums ----------------
__global__ void hist1_kernel(const float* __restrict__ pred,
                             const float* __restrict__ targ,
                             uint32_t* __restrict__ ws) {
    __shared__ uint32_t lh[2 * NB1];
    const int b = blockIdx.y;
    for (int i = threadIdx.x; i < 2 * NB1; i += blockDim.x) lh[i] = 0;
    __syncthreads();
    const float4* pb = (const float4*)(pred + (size_t)b * NPX);
    const float4* tb = (const float4*)(targ + (size_t)b * NPX);
    uint32_t nloc = 0;
    float sump = 0.f, sumt = 0.f;
    const int stride = gridDim.x * blockDim.x;
    for (int q = blockIdx.x * blockDim.x + threadIdx.x; q < NPX / 4; q += stride) {
        float4 tv = tb[q], pv = pb[q];
        float tA[4] = {tv.x, tv.y, tv.z, tv.w};
        float pA[4] = {pv.x, pv.y, pv.z, pv.w};
        #pragma unroll
        for (int k = 0; k < 4; k++) {
            float t = tA[k];
            if (t > 0.f) {
                float p = pA[k];
                nloc++; sumt += t; sump += p;
                atomicAdd(&lh[fmap(p) >> 21], 1u);
                atomicAdd(&lh[NB1 + (fmap(t) >> 21)], 1u);
            }
        }
    }
    __syncthreads();
    uint32_t* hist = ws + HIST_OFF;
    for (int i = threadIdx.x; i < 2 * NB1; i += blockDim.x) {
        uint32_t v = lh[i];
        if (v) {
            int which = i >> 11, bin = i & (NB1 - 1);
            atomicAdd(&hist[(size_t)(which * B + b) * NB1 + bin], v);
        }
    }
    for (int off = 32; off; off >>= 1) {
        nloc += __shfl_down(nloc, off, 64);
        sump += __shfl_down(sump, off, 64);
        sumt += __shfl_down(sumt, off, 64);
    }
    if ((threadIdx.x & 63) == 0) {
        if (nloc) atomicAdd(ws + N_OFF + b, nloc);
        atomicAdd(((float*)(ws + TSUM_OFF)) + b, sump);
        atomicAdd(((float*)(ws + TSUM_OFF)) + B + b, sumt);
    }
}

// ---------------- stage 2: mid-11-bit histogram + sum-below-stage1-bin ----------------
__global__ void hist2_kernel(const float* __restrict__ pred,
                             const float* __restrict__ targ,
                             uint32_t* __restrict__ ws) {
    __shared__ uint32_t lh[2 * NB1];
    const int b = blockIdx.y;
    for (int i = threadIdx.x; i < 2 * NB1; i += blockDim.x) lh[i] = 0;
    const uint32_t pfxp = ws[PFX_OFF + b];
    const uint32_t pfxt = ws[PFX_OFF + B + b];
    __syncthreads();
    const float4* pb = (const float4*)(pred + (size_t)b * NPX);
    const float4* tb = (const float4*)(targ + (size_t)b * NPX);
    float sbp = 0.f, sbt = 0.f;
    const int stride = gridDim.x * blockDim.x;
    for (int q = blockIdx.x * blockDim.x + threadIdx.x; q < NPX / 4; q += stride) {
        float4 tv = tb[q], pv = pb[q];
        float tA[4] = {tv.x, tv.y, tv.z, tv.w};
        float pA[4] = {pv.x, pv.y, pv.z, pv.w};
        #pragma unroll
        for (int k = 0; k < 4; k++) {
            float t = tA[k];
            if (t > 0.f) {
                float p = pA[k];
                uint32_t up = fmap(p), u1 = up >> 21;
                if (u1 < pfxp) sbp += p;
                else if (u1 == pfxp) atomicAdd(&lh[(up >> 10) & 2047u], 1u);
                uint32_t ut = fmap(t), v1 = ut >> 21;
                if (v1 < pfxt) sbt += t;
                else if (v1 == pfxt) atomicAdd(&lh[NB1 + ((ut >> 10) & 2047u)], 1u);
            }
        }
    }
    __syncthreads();
    uint32_t* hist = ws + HIST_OFF;
    for (int i = threadIdx.x; i < 2 * NB1; i += blockDim.x) {
        uint32_t v = lh[i];
        if (v) {
            int which = i >> 11, bin = i & (NB1 - 1);
            atomicAdd(&hist[(size_t)(which * B + b) * NB1 + bin], v);
        }
    }
    for (int off = 32; off; off >>= 1) {
        sbp += __shfl_down(sbp, off, 64);
        sbt += __shfl_down(sbt, off, 64);
    }
    if ((threadIdx.x & 63) == 0) {
        atomicAdd(((float*)(ws + SB_OFF)) + b, sbp);
        atomicAdd(((float*)(ws + SB_OFF)) + B + b, sbt);
    }
}

// ---------------- stage 3: low-10-bit hist + per-bin value sums + sum-below ----------------
__global__ void hist3_kernel(const float* __restrict__ pred,
                             const float* __restrict__ targ,
                             uint32_t* __restrict__ ws) {
    __shared__ uint32_t lc[2 * NB3];
    __shared__ float    lsm[2 * NB3];
    const int b = blockIdx.y;
    for (int i = threadIdx.x; i < 2 * NB3; i += blockDim.x) { lc[i] = 0; lsm[i] = 0.f; }
    const uint32_t pfx2p = ws[PFX_OFF + b];       // 22-bit
    const uint32_t pfx2t = ws[PFX_OFF + B + b];
    const uint32_t pfx1p = pfx2p >> 11;
    const uint32_t pfx1t = pfx2t >> 11;
    __syncthreads();
    const float4* pb = (const float4*)(pred + (size_t)b * NPX);
    const float4* tb = (const float4*)(targ + (size_t)b * NPX);
    float sbp = 0.f, sbt = 0.f;
    const int stride = gridDim.x * blockDim.x;
    for (int q = blockIdx.x * blockDim.x + threadIdx.x; q < NPX / 4; q += stride) {
        float4 tv = tb[q], pv = pb[q];
        float tA[4] = {tv.x, tv.y, tv.z, tv.w};
        float pA[4] = {pv.x, pv.y, pv.z, pv.w};
        #pragma unroll
        for (int k = 0; k < 4; k++) {
            float t = tA[k];
            if (t > 0.f) {
                float p = pA[k];
                uint32_t up = fmap(p), u21 = up >> 10;
                if ((u21 >> 11) == pfx1p) {
                    if (u21 < pfx2p) sbp += p;
                    else if (u21 == pfx2p) {
                        uint32_t bin = up & 1023u;
                        atomicAdd(&lc[bin], 1u);
                        atomicAdd(&lsm[bin], p);
                    }
                }
                uint32_t ut = fmap(t), v21 = ut >> 10;
                if ((v21 >> 11) == pfx1t) {
                    if (v21 < pfx2t) sbt += t;
                    else if (v21 == pfx2t) {
                        uint32_t bin = ut & 1023u;
                        atomicAdd(&lc[NB3 + bin], 1u);
                        atomicAdd(&lsm[NB3 + bin], t);
                    }
                }
            }
        }
    }
    __syncthreads();
    uint32_t* hist = ws + HIST_OFF;
    for (int i = threadIdx.x; i < 2 * NB3; i += blockDim.x) {
        uint32_t v = lc[i];
        if (v) {
            int which = i >> 10, bin = i & (NB3 - 1);
            uint32_t* slot = &hist[(size_t)(which * B + b) * NB1];
            atomicAdd(&slot[bin], v);
            atomicAdd((float*)&slot[NB3 + bin], lsm[i]);
        }
    }
    for (int off = 32; off; off >>= 1) {
        sbp += __shfl_down(sbp, off, 64);
        sbt += __shfl_down(sbt, off, 64);
    }
    if ((threadIdx.x & 63) == 0) {
        atomicAdd(((float*)(ws + SB_OFF)) + b, sbp);
        atomicAdd(((float*)(ws + SB_OFF)) + B + b, sbt);
    }
}

// ---------------- select stages 1/2 (counts only, 2048 bins) ----------------
template <int STAGE>
__global__ void select_kernel(uint32_t* __restrict__ ws) {
    const int b = blockIdx.x, which = blockIdx.y;
    const uint32_t* h = ws + HIST_OFF + (size_t)(which * B + b) * NB1;
    uint32_t* karr = ws + K_OFF + which * B;
    uint32_t* parr = ws + PFX_OFF + which * B;
    const uint32_t k = (STAGE == 1) ? ((ws[N_OFF + b] - 1u) >> 1) : karr[b];
    const int t = threadIdx.x;
    uint32_t mysum = 0;
    #pragma unroll
    for (int i = 0; i < 8; i++) mysum += h[t * 8 + i];
    __shared__ uint32_t s[256];
    s[t] = mysum;
    __syncthreads();
    for (int off = 1; off < 256; off <<= 1) {
        uint32_t add = (t >= off) ? s[t - off] : 0u;
        __syncthreads();
        s[t] += add;
        __syncthreads();
    }
    uint32_t incl = s[t], excl = incl - mysum;
    if (k >= excl && k < incl) {
        uint32_t c = excl, bin = 0, newk = 0;
        for (int i = 0; i < 8; i++) {
            uint32_t hv = h[t * 8 + i];
            if (k < c + hv) { bin = t * 8 + i; newk = k - c; break; }
            c += hv;
        }
        if (STAGE == 1) { parr[b] = bin; karr[b] = newk; }
        else            { parr[b] = (parr[b] << 11) | bin; karr[b] = newk; }
    }
}

// ---------------- select stage 3 (counts + value-sum prefix) ----------------
__global__ void select3_kernel(uint32_t* __restrict__ ws) {
    const int b = blockIdx.x, which = blockIdx.y;
    const uint32_t* h = ws + HIST_OFF + (size_t)(which * B + b) * NB1;
    const float* hs = (const float*)(h + NB3);
    const uint32_t k = ws[K_OFF + which * B + b];
    const int t = threadIdx.x;
    uint32_t mysum = 0; float myfs = 0.f;
    #pragma unroll
    for (int i = 0; i < 4; i++) { mysum += h[t * 4 + i]; myfs += hs[t * 4 + i]; }
    __shared__ uint32_t s[256];
    __shared__ float sf[256];
    s[t] = mysum; sf[t] = myfs;
    __syncthreads();
    for (int off = 1; off < 256; off <<= 1) {
        uint32_t add = (t >= off) ? s[t - off] : 0u;
        float addf = (t >= off) ? sf[t - off] : 0.f;
        __syncthreads();
        s[t] += add; sf[t] += addf;
        __syncthreads();
    }
    uint32_t incl = s[t], excl = incl - mysum;
    float fexcl = sf[t] - myfs;
    if (k >= excl && k < incl) {
        uint32_t c = excl, bin = 0, newk = 0, e = 0;
        float fs = fexcl;
        for (int i = 0; i < 4; i++) {
            uint32_t hv = h[t * 4 + i];
            if (k < c + hv) { bin = t * 4 + i; newk = k - c; e = hv; break; }
            c += hv;
            fs += hs[t * 4 + i];
        }
        uint32_t u = (ws[PFX_OFF + which * B + b] << 10) | bin;
        ((float*)(ws + SH_OFF))[which * B + b] = funmap(u);
        ws[K_OFF + which * B + b] = newk;
        ws[EQ_OFF + which * B + b] = e;
        ((float*)(ws + SB_OFF))[which * B + b] += fs;   // below-median sum within prefix group
    }
}

// ---------------- params: scales from sum decomposition, c2, trim threshold ----------------
__global__ void param_kernel(const float* __restrict__ pred,
                             const float* __restrict__ targ,
                             uint32_t* __restrict__ ws) {
    const int b = threadIdx.x;
    if (b >= B) return;
    const uint32_t n = ws[N_OFF + b];
    const uint32_t k0 = (n - 1u) >> 1;
    float med[2], rs[2];
    uint32_t nab[2];
    #pragma unroll
    for (int w = 0; w < 2; w++) {
        float m = ((const float*)(ws + SH_OFF))[w * B + b];
        uint32_t k3 = ws[K_OFF + w * B + b];
        uint32_t e = ws[EQ_OFF + w * B + b];
        float SBv = ((const float*)(ws + SB_OFF))[w * B + b];
        float ST = ((const float*)(ws + TSUM_OFF))[w * B + b];
        uint32_t CB = k0 - k3;                    // count strictly below median
        uint32_t na = n - CB - e;                 // count strictly above
        float Sab = ST - SBv - (float)e * m;      // sum of values above median
        float absdev = (Sab - (float)na * m) + ((float)CB * m - SBv);
        float scale = absdev / (float)n;
        med[w] = m; nab[w] = na;
        rs[w] = 1.f / scale;
        ((float*)(ws + RS_OFF))[w * B + b] = rs[w];
    }
    uint32_t c2 = nab[1];                         // count(targ > st)
    ws[C2_OFF + b] = c2;
    uint32_t mi = (uint32_t)NPX - c2 + (uint32_t)TRIM_IDX;
    if (mi > (uint32_t)(NPX - 1)) mi = NPX - 1;
    float p = pred[(size_t)b * NPX + mi];
    float t = targ[(size_t)b * NPX + mi];
    float pn = (p - med[0]) * rs[0], tn = (t - med[1]) * rs[1];
    ((float*)(ws + THR_OFF))[b] = (tn > 0.f) ? fabsf(pn - tn) : 0.f;
}

// ---------------- fused loss: one wave per row; ALL loads hoisted upfront ----------------
__global__ void __launch_bounds__(256) loss_kernel(const float* __restrict__ pred,
                                                   const float* __restrict__ targ,
                                                   uint32_t* __restrict__ ws) {
    const int wid = (blockIdx.x << 2) + (threadIdx.x >> 6);   // global wave = row
    const int b = wid / H;
    const int i = wid - b * H;
    const int l = threadIdx.x & 63;
    const float sp = ((const float*)(ws + SH_OFF))[b];
    const float st = ((const float*)(ws + SH_OFF))[B + b];
    const float rp = ((const float*)(ws + RS_OFF))[b];
    const float rt = ((const float*)(ws + RS_OFF))[B + b];
    const float thr = ((const float*)(ws + THR_OFF))[b];
    const float* Pp = pred + (size_t)b * NPX;
    const float* Tp = targ + (size_t)b * NPX;
    const int ro = i * W + l * 8;

    const bool v1 = i >= 1;
    const bool r2 = (i & 1) == 0;
    const bool r4 = (i & 3) == 0;
    const bool r8 = (i & 7) == 0;
    const bool v2 = r2 && i >= 2;
    const bool v4 = r4 && i >= 4;
    const bool v8 = r8 && i >= 8;
    const int ro1 = v1 ? ro - W : ro;        // clamped: invalid -> own row, gated by predicate
    const int ro2 = v2 ? ro - 2 * W : ro;
    const int ro4 = v4 ? ro - 4 * W : ro;
    const int ro8 = v8 ? ro - 8 * W : ro;

    // ---- issue ALL loads back-to-back (no conditional bodies) ----
    float4 tA0 = *(const float4*)(Tp + ro),     tA1 = *(const float4*)(Tp + ro + 4);
    float4 pA0 = *(const float4*)(Pp + ro),     pA1 = *(const float4*)(Pp + ro + 4);
    float4 tB0 = *(const float4*)(Tp + ro1),    tB1 = *(const float4*)(Tp + ro1 + 4);
    float4 pB0 = *(const float4*)(Pp + ro1),    pB1 = *(const float4*)(Pp + ro1 + 4);
    float4 tC0 = *(const float4*)(Tp + ro2),    tC1 = *(const float4*)(Tp + ro2 + 4);
    float4 pC0 = *(const float4*)(Pp + ro2),    pC1 = *(const float4*)(Pp + ro2 + 4);
    float t4a = Tp[ro4], t4b = Tp[ro4 + 4];
    float p4a = Pp[ro4], p4b = Pp[ro4 + 4];
    float t8a = Tp[ro8];
    float p8a = Pp[ro8];

    float t[8] = {tA0.x,tA0.y,tA0.z,tA0.w,tA1.x,tA1.y,tA1.z,tA1.w};
    float p[8] = {pA0.x,pA0.y,pA0.z,pA0.w,pA1.x,pA1.y,pA1.z,pA1.w};
    float pn[8]; bool m[8];
    #pragma unroll
    for (int k = 0; k < 8; k++) { pn[k] = (p[k] - sp) * rp; m[k] = t[k] > st; }

    float tl = 0.f, gl0 = 0.f, gl1 = 0.f, gl2 = 0.f, gl3 = 0.f;
    uint32_t mc = 0;

    #pragma unroll
    for (int k = 0; k < 8; k++) {
        if (m[k]) {
            float tn = (t[k] - st) * rt;
            float r = fabsf(pn[k] - tn);
            if (r <= thr) tl += r;
        }
    }
    // cross-lane left neighbors (cols l*8-1, -2, -4, -8)
    float t7p = __shfl_up(t[7], 1), pn7p = __shfl_up(pn[7], 1);
    float t6p = __shfl_up(t[6], 1), pn6p = __shfl_up(pn[6], 1);
    float t4p = __shfl_up(t[4], 1), pn4p = __shfl_up(pn[4], 1);
    float t0p = __shfl_up(t[0], 1), pn0p = __shfl_up(pn[0], 1);

    // scale 0 horizontal
    if (l > 0 && m[0] && t7p > st) gl0 += fabsf(pn[0] - pn7p);
    #pragma unroll
    for (int k = 1; k < 8; k++) if (m[k] && m[k - 1]) gl0 += fabsf(pn[k] - pn[k - 1]);
    // scale 0 vertical (row i-1)
    if (v1) {
        float tu[8] = {tB0.x,tB0.y,tB0.z,tB0.w,tB1.x,tB1.y,tB1.z,tB1.w};
        float pu[8] = {pB0.x,pB0.y,pB0.z,pB0.w,pB1.x,pB1.y,pB1.z,pB1.w};
        #pragma unroll
        for (int k = 0; k < 8; k++)
            if (m[k] && tu[k] > st) gl0 += fabsf(pn[k] - (pu[k] - sp) * rp);
    }
    if (r2) {   // scale 1 (step 2)
        mc += (uint32_t)m[0] + m[2] + m[4] + m[6];
        if (l > 0 && m[0] && t6p > st) gl1 += fabsf(pn[0] - pn6p);
        if (m[2] && m[0]) gl1 += fabsf(pn[2] - pn[0]);
        if (m[4] && m[2]) gl1 += fabsf(pn[4] - pn[2]);
        if (m[6] && m[4]) gl1 += fabsf(pn[6] - pn[4]);
        if (v2) {
            if (m[0] && tC0.x > st) gl1 += fabsf(pn[0] - (pC0.x - sp) * rp);
            if (m[2] && tC0.z > st) gl1 += fabsf(pn[2] - (pC0.z - sp) * rp);
            if (m[4] && tC1.x > st) gl1 += fabsf(pn[4] - (pC1.x - sp) * rp);
            if (m[6] && tC1.z > st) gl1 += fabsf(pn[6] - (pC1.z - sp) * rp);
        }
        if (r4) {   // scale 2 (step 4)
            mc += ((uint32_t)m[0] + m[4]) << 10;
            if (l > 0 && m[0] && t4p > st) gl2 += fabsf(pn[0] - pn4p);
            if (m[4] && m[0]) gl2 += fabsf(pn[4] - pn[0]);
            if (v4) {
                if (m[0] && t4a > st) gl2 += fabsf(pn[0] - (p4a - sp) * rp);
                if (m[4] && t4b > st) gl2 += fabsf(pn[4] - (p4b - sp) * rp);
            }
            if (r8) {   // scale 3 (step 8)
                mc += ((uint32_t)m[0]) << 20;
                if (l > 0 && m[0] && t0p > st) gl3 += fabsf(pn[0] - pn0p);
                if (v8) {
                    if (m[0] && t8a > st) gl3 += fabsf(pn[0] - (p8a - sp) * rp);
                }
            }
        }
    }
    for (int off = 32; off; off >>= 1) {
        tl  += __shfl_down(tl, off, 64);
        gl0 += __shfl_down(gl0, off, 64);
        gl1 += __shfl_down(gl1, off, 64);
        gl2 += __shfl_down(gl2, off, 64);
        gl3 += __shfl_down(gl3, off, 64);
        mc  += __shfl_down(mc, off, 64);
    }
    if (l == 0) {
        float* gs = (float*)(ws + GS_OFF);
        atomicAdd(((float*)(ws + TS_OFF)) + b, tl);
        atomicAdd(gs + b, gl0);
        if (r2) {
            atomicAdd(gs + B + b, gl1);
            atomicAdd(ws + MS_OFF + b, mc & 1023u);
            if (r4) {
                atomicAdd(gs + 2 * B + b, gl2);
                atomicAdd(ws + MS_OFF + B + b, (mc >> 10) & 1023u);
                if (r8) {
                    atomicAdd(gs + 3 * B + b, gl3);
                    atomicAdd(ws + MS_OFF + 2 * B + b, (mc >> 20) & 1023u);
                }
            }
        }
    }
}

// ---------------- finalize ----------------
__global__ void finalize_kernel(const uint32_t* __restrict__ ws, float* __restrict__ out) {
    const int b = threadIdx.x;
    float v = 0.f;
    if (b < B) {
        float c2 = (float)ws[C2_OFF + b];
        const float* tsum = (const float*)(ws + TS_OFF);
        const float* gsum = (const float*)(ws + GS_OFF);
        float tm = (c2 > 0.f) ? tsum[b] / (2.f * c2) : 0.f;
        float g = (c2 > 0.f) ? gsum[b] / c2 : 0.f;
        for (int z = 0; z < 3; z++) {
            float ms = (float)ws[MS_OFF + z * B + b];
            g += (ms > 0.f) ? gsum[(1 + z) * B + b] / ms : 0.f;
        }
        v = tm + 0.5f * g;
    }
    for (int off = 32; off; off >>= 1) v += __shfl_down(v, off, 64);
    if (b == 0) out[0] = v * (1.f / 64.f);
}

extern "C" void kernel_launch(void* const* d_in, const int* in_sizes, int n_in,
                              void* d_out, int out_size, void* d_ws, size_t ws_size,
                              hipStream_t stream) {
    const float* pred = (const float*)d_in[0];
    const float* targ = (const float*)d_in[1];
    float* out = (float*)d_out;
    uint32_t* ws = (uint32_t*)d_ws;

    hipMemsetAsync(ws, 0, (size_t)ZERO_U32 * 4, stream);

    dim3 hb(1024), hg(8, B);   // 512 blocks x 1024 thr = 2 blocks/CU, 32 waves/CU
    hist1_kernel<<<hg, hb, 0, stream>>>(pred, targ, ws);
    select_kernel<1><<<dim3(B, 2), 256, 0, stream>>>(ws);

    hipMemsetAsync(ws, 0, (size_t)HIST_U32 * 4, stream);
    hist2_kernel<<<hg, hb, 0, stream>>>(pred, targ, ws);
    select_kernel<2><<<dim3(B, 2), 256, 0, stream>>>(ws);

    hipMemsetAsync(ws, 0, (size_t)HIST_U32 * 4, stream);
    hist3_kernel<<<hg, hb, 0, stream>>>(pred, targ, ws);
    select3_kernel<<<dim3(B, 2), 256, 0, stream>>>(ws);

    param_kernel<<<1, 64, 0, stream>>>(pred, targ, ws);
    loss_kernel<<<dim3((B * H) / 4), 256, 0, stream>>>(pred, targ, ws);
    finalize_kernel<<<1, 64, 0, stream>>>(ws, out);
}

// Round 5
// 284.036 us; speedup vs baseline: 1.6745x; 1.6745x over previous
//
#include <hip/hip_runtime.h>
#include <stdint.h>

#define B 64
#define H 384
#define W 512
#define NPX (H*W)            // 196608
#define TRIM_IDX 157286      // int(0.8 * 196608)
#define RPW 8                // rows per wave in loss kernel

#define NB1 2048             // stage1/2 bins (11 bits)
#define NB3 1024             // stage3 bins (10 bits)

// ---- workspace layout (uint32 units) ----
#define HIST_OFF 0
#define HIST_U32 (2*B*NB1)               // 262144 u32 = 1 MB
#define ACC_OFF  (HIST_OFF + HIST_U32)
#define N_OFF    (ACC_OFF + 0)           // [B]  u32 mask count (targ>0)
#define MS_OFF   (ACC_OFF + 64)          // [3][B] u32 subsample mask counts
#define TS_OFF   (ACC_OFF + 256)         // [B]  f32 tmae sum
#define GS_OFF   (ACC_OFF + 320)         // [4][B] f32 grad sums
#define TSUM_OFF (ACC_OFF + 576)         // [2][B] f32 total masked value sum
#define SB_OFF   (ACC_OFF + 704)         // [2][B] f32 sum of masked values < med
#define ZERO_U32 (HIST_U32 + 832)        // zero [0, ZERO_U32) at launch
// persistent (written before read each launch, not zeroed)
#define K_OFF    (ACC_OFF + 832)         // [2][B] u32 remaining rank
#define PFX_OFF  (ACC_OFF + 960)         // [2][B] u32 selected bit prefix
#define EQ_OFF   (ACC_OFF + 1088)        // [2][B] u32 count equal to median
#define SH_OFF   (ACC_OFF + 1216)        // [2][B] f32 median (shift)
#define RS_OFF   (ACC_OFF + 1344)        // [2][B] f32 reciprocal scale
#define THR_OFF  (ACC_OFF + 1472)        // [B]  f32 trim threshold
#define C2_OFF   (ACC_OFF + 1536)        // [B]  u32 count targ>shift_t

__device__ __forceinline__ uint32_t fmap(float f) {
    uint32_t b = __float_as_uint(f);
    return (b & 0x80000000u) ? ~b : (b | 0x80000000u);
}
__device__ __forceinline__ float funmap(uint32_t u) {
    uint32_t b = (u & 0x80000000u) ? (u & 0x7fffffffu) : ~u;
    return __uint_as_float(b);
}

// ---------------- stage 1: 11-bit histogram + n + total sums ----------------
__global__ void hist1_kernel(const float* __restrict__ pred,
                             const float* __restrict__ targ,
                             uint32_t* __restrict__ ws) {
    __shared__ uint32_t lh[2 * NB1];
    const int b = blockIdx.y;
    for (int i = threadIdx.x; i < 2 * NB1; i += blockDim.x) lh[i] = 0;
    __syncthreads();
    const float4* pb = (const float4*)(pred + (size_t)b * NPX);
    const float4* tb = (const float4*)(targ + (size_t)b * NPX);
    uint32_t nloc = 0;
    float sump = 0.f, sumt = 0.f;
    const int stride = gridDim.x * blockDim.x;
    for (int q = blockIdx.x * blockDim.x + threadIdx.x; q < NPX / 4; q += stride) {
        float4 tv = tb[q], pv = pb[q];
        float tA[4] = {tv.x, tv.y, tv.z, tv.w};
        float pA[4] = {pv.x, pv.y, pv.z, pv.w};
        #pragma unroll
        for (int k = 0; k < 4; k++) {
            float t = tA[k];
            if (t > 0.f) {
                float p = pA[k];
                nloc++; sumt += t; sump += p;
                atomicAdd(&lh[fmap(p) >> 21], 1u);
                atomicAdd(&lh[NB1 + (fmap(t) >> 21)], 1u);
            }
        }
    }
    __syncthreads();
    uint32_t* hist = ws + HIST_OFF;
    for (int i = threadIdx.x; i < 2 * NB1; i += blockDim.x) {
        uint32_t v = lh[i];
        if (v) {
            int which = i >> 11, bin = i & (NB1 - 1);
            atomicAdd(&hist[(size_t)(which * B + b) * NB1 + bin], v);
        }
    }
    for (int off = 32; off; off >>= 1) {
        nloc += __shfl_down(nloc, off, 64);
        sump += __shfl_down(sump, off, 64);
        sumt += __shfl_down(sumt, off, 64);
    }
    if ((threadIdx.x & 63) == 0) {
        if (nloc) atomicAdd(ws + N_OFF + b, nloc);
        atomicAdd(((float*)(ws + TSUM_OFF)) + b, sump);
        atomicAdd(((float*)(ws + TSUM_OFF)) + B + b, sumt);
    }
}

// ---------------- stage 2: mid-11-bit histogram + sum-below-stage1-bin ----------------
__global__ void hist2_kernel(const float* __restrict__ pred,
                             const float* __restrict__ targ,
                             uint32_t* __restrict__ ws) {
    __shared__ uint32_t lh[2 * NB1];
    const int b = blockIdx.y;
    for (int i = threadIdx.x; i < 2 * NB1; i += blockDim.x) lh[i] = 0;
    const uint32_t pfxp = ws[PFX_OFF + b];
    const uint32_t pfxt = ws[PFX_OFF + B + b];
    __syncthreads();
    const float4* pb = (const float4*)(pred + (size_t)b * NPX);
    const float4* tb = (const float4*)(targ + (size_t)b * NPX);
    float sbp = 0.f, sbt = 0.f;
    const int stride = gridDim.x * blockDim.x;
    for (int q = blockIdx.x * blockDim.x + threadIdx.x; q < NPX / 4; q += stride) {
        float4 tv = tb[q], pv = pb[q];
        float tA[4] = {tv.x, tv.y, tv.z, tv.w};
        float pA[4] = {pv.x, pv.y, pv.z, pv.w};
        #pragma unroll
        for (int k = 0; k < 4; k++) {
            float t = tA[k];
            if (t > 0.f) {
                float p = pA[k];
                uint32_t up = fmap(p), u1 = up >> 21;
                if (u1 < pfxp) sbp += p;
                else if (u1 == pfxp) atomicAdd(&lh[(up >> 10) & 2047u], 1u);
                uint32_t ut = fmap(t), v1 = ut >> 21;
                if (v1 < pfxt) sbt += t;
                else if (v1 == pfxt) atomicAdd(&lh[NB1 + ((ut >> 10) & 2047u)], 1u);
            }
        }
    }
    __syncthreads();
    uint32_t* hist = ws + HIST_OFF;
    for (int i = threadIdx.x; i < 2 * NB1; i += blockDim.x) {
        uint32_t v = lh[i];
        if (v) {
            int which = i >> 11, bin = i & (NB1 - 1);
            atomicAdd(&hist[(size_t)(which * B + b) * NB1 + bin], v);
        }
    }
    for (int off = 32; off; off >>= 1) {
        sbp += __shfl_down(sbp, off, 64);
        sbt += __shfl_down(sbt, off, 64);
    }
    if ((threadIdx.x & 63) == 0) {
        atomicAdd(((float*)(ws + SB_OFF)) + b, sbp);
        atomicAdd(((float*)(ws + SB_OFF)) + B + b, sbt);
    }
}

// ---------------- stage 3: low-10-bit hist + per-bin value sums + sum-below ----------------
__global__ void hist3_kernel(const float* __restrict__ pred,
                             const float* __restrict__ targ,
                             uint32_t* __restrict__ ws) {
    __shared__ uint32_t lc[2 * NB3];
    __shared__ float    lsm[2 * NB3];
    const int b = blockIdx.y;
    for (int i = threadIdx.x; i < 2 * NB3; i += blockDim.x) { lc[i] = 0; lsm[i] = 0.f; }
    const uint32_t pfx2p = ws[PFX_OFF + b];       // 22-bit
    const uint32_t pfx2t = ws[PFX_OFF + B + b];
    const uint32_t pfx1p = pfx2p >> 11;
    const uint32_t pfx1t = pfx2t >> 11;
    __syncthreads();
    const float4* pb = (const float4*)(pred + (size_t)b * NPX);
    const float4* tb = (const float4*)(targ + (size_t)b * NPX);
    float sbp = 0.f, sbt = 0.f;
    const int stride = gridDim.x * blockDim.x;
    for (int q = blockIdx.x * blockDim.x + threadIdx.x; q < NPX / 4; q += stride) {
        float4 tv = tb[q], pv = pb[q];
        float tA[4] = {tv.x, tv.y, tv.z, tv.w};
        float pA[4] = {pv.x, pv.y, pv.z, pv.w};
        #pragma unroll
        for (int k = 0; k < 4; k++) {
            float t = tA[k];
            if (t > 0.f) {
                float p = pA[k];
                uint32_t up = fmap(p), u21 = up >> 10;
                if ((u21 >> 11) == pfx1p) {
                    if (u21 < pfx2p) sbp += p;
                    else if (u21 == pfx2p) {
                        uint32_t bin = up & 1023u;
                        atomicAdd(&lc[bin], 1u);
                        atomicAdd(&lsm[bin], p);
                    }
                }
                uint32_t ut = fmap(t), v21 = ut >> 10;
                if ((v21 >> 11) == pfx1t) {
                    if (v21 < pfx2t) sbt += t;
                    else if (v21 == pfx2t) {
                        uint32_t bin = ut & 1023u;
                        atomicAdd(&lc[NB3 + bin], 1u);
                        atomicAdd(&lsm[NB3 + bin], t);
                    }
                }
            }
        }
    }
    __syncthreads();
    uint32_t* hist = ws + HIST_OFF;
    for (int i = threadIdx.x; i < 2 * NB3; i += blockDim.x) {
        uint32_t v = lc[i];
        if (v) {
            int which = i >> 10, bin = i & (NB3 - 1);
            uint32_t* slot = &hist[(size_t)(which * B + b) * NB1];
            atomicAdd(&slot[bin], v);
            atomicAdd((float*)&slot[NB3 + bin], lsm[i]);
        }
    }
    for (int off = 32; off; off >>= 1) {
        sbp += __shfl_down(sbp, off, 64);
        sbt += __shfl_down(sbt, off, 64);
    }
    if ((threadIdx.x & 63) == 0) {
        atomicAdd(((float*)(ws + SB_OFF)) + b, sbp);
        atomicAdd(((float*)(ws + SB_OFF)) + B + b, sbt);
    }
}

// ---------------- select stages 1/2 (counts only) + zero own hist slice ----------------
template <int STAGE>
__global__ void select_kernel(uint32_t* __restrict__ ws) {
    const int b = blockIdx.x, which = blockIdx.y;
    uint32_t* h = ws + HIST_OFF + (size_t)(which * B + b) * NB1;
    uint32_t* karr = ws + K_OFF + which * B;
    uint32_t* parr = ws + PFX_OFF + which * B;
    const uint32_t k = (STAGE == 1) ? ((ws[N_OFF + b] - 1u) >> 1) : karr[b];
    const int t = threadIdx.x;
    uint32_t mysum = 0;
    #pragma unroll
    for (int i = 0; i < 8; i++) mysum += h[t * 8 + i];
    __shared__ uint32_t s[256];
    s[t] = mysum;
    __syncthreads();
    for (int off = 1; off < 256; off <<= 1) {
        uint32_t add = (t >= off) ? s[t - off] : 0u;
        __syncthreads();
        s[t] += add;
        __syncthreads();
    }
    uint32_t incl = s[t], excl = incl - mysum;
    if (k >= excl && k < incl) {
        uint32_t c = excl, bin = 0, newk = 0;
        for (int i = 0; i < 8; i++) {
            uint32_t hv = h[t * 8 + i];
            if (k < c + hv) { bin = t * 8 + i; newk = k - c; break; }
            c += hv;
        }
        if (STAGE == 1) { parr[b] = bin; karr[b] = newk; }
        else            { parr[b] = (parr[b] << 11) | bin; karr[b] = newk; }
    }
    __syncthreads();                 // winner's reads done before zeroing
    #pragma unroll
    for (int i = 0; i < 8; i++) h[t * 8 + i] = 0;   // hist ready for next pass
}

// ---------------- select stage 3 (counts + value-sum prefix) + zero slice ----------------
__global__ void select3_kernel(uint32_t* __restrict__ ws) {
    const int b = blockIdx.x, which = blockIdx.y;
    uint32_t* h = ws + HIST_OFF + (size_t)(which * B + b) * NB1;
    const float* hs = (const float*)(h + NB3);
    const uint32_t k = ws[K_OFF + which * B + b];
    const int t = threadIdx.x;
    uint32_t mysum = 0; float myfs = 0.f;
    #pragma unroll
    for (int i = 0; i < 4; i++) { mysum += h[t * 4 + i]; myfs += hs[t * 4 + i]; }
    __shared__ uint32_t s[256];
    __shared__ float sf[256];
    s[t] = mysum; sf[t] = myfs;
    __syncthreads();
    for (int off = 1; off < 256; off <<= 1) {
        uint32_t add = (t >= off) ? s[t - off] : 0u;
        float addf = (t >= off) ? sf[t - off] : 0.f;
        __syncthreads();
        s[t] += add; sf[t] += addf;
        __syncthreads();
    }
    uint32_t incl = s[t], excl = incl - mysum;
    float fexcl = sf[t] - myfs;
    if (k >= excl && k < incl) {
        uint32_t c = excl, bin = 0, newk = 0, e = 0;
        float fs = fexcl;
        for (int i = 0; i < 4; i++) {
            uint32_t hv = h[t * 4 + i];
            if (k < c + hv) { bin = t * 4 + i; newk = k - c; e = hv; break; }
            c += hv;
            fs += hs[t * 4 + i];
        }
        uint32_t u = (ws[PFX_OFF + which * B + b] << 10) | bin;
        ((float*)(ws + SH_OFF))[which * B + b] = funmap(u);
        ws[K_OFF + which * B + b] = newk;
        ws[EQ_OFF + which * B + b] = e;
        ((float*)(ws + SB_OFF))[which * B + b] += fs;
    }
    __syncthreads();
    #pragma unroll
    for (int i = 0; i < 8; i++) h[t * 8 + i] = 0;
}

// ---------------- params: scales from sum decomposition, c2, trim threshold ----------------
__global__ void param_kernel(const float* __restrict__ pred,
                             const float* __restrict__ targ,
                             uint32_t* __restrict__ ws) {
    const int b = threadIdx.x;
    if (b >= B) return;
    const uint32_t n = ws[N_OFF + b];
    const uint32_t k0 = (n - 1u) >> 1;
    float med[2], rs[2];
    uint32_t nab[2];
    #pragma unroll
    for (int w = 0; w < 2; w++) {
        float m = ((const float*)(ws + SH_OFF))[w * B + b];
        uint32_t k3 = ws[K_OFF + w * B + b];
        uint32_t e = ws[EQ_OFF + w * B + b];
        float SBv = ((const float*)(ws + SB_OFF))[w * B + b];
        float ST = ((const float*)(ws + TSUM_OFF))[w * B + b];
        uint32_t CB = k0 - k3;                    // count strictly below median
        uint32_t na = n - CB - e;                 // count strictly above
        float Sab = ST - SBv - (float)e * m;      // sum of values above median
        float absdev = (Sab - (float)na * m) + ((float)CB * m - SBv);
        float scale = absdev / (float)n;
        med[w] = m; nab[w] = na;
        rs[w] = 1.f / scale;
        ((float*)(ws + RS_OFF))[w * B + b] = rs[w];
    }
    uint32_t c2 = nab[1];                         // count(targ > st)
    ws[C2_OFF + b] = c2;
    uint32_t mi = (uint32_t)NPX - c2 + (uint32_t)TRIM_IDX;
    if (mi > (uint32_t)(NPX - 1)) mi = NPX - 1;
    float p = pred[(size_t)b * NPX + mi];
    float t = targ[(size_t)b * NPX + mi];
    float pn = (p - med[0]) * rs[0], tn = (t - med[1]) * rs[1];
    ((float*)(ws + THR_OFF))[b] = (tn > 0.f) ? fabsf(pn - tn) : 0.f;
}

// ---------------- fused loss: 8-row strip per wave, 2-deep register ring ----------------
__global__ void __launch_bounds__(256) loss_kernel(const float* __restrict__ pred,
                                                   const float* __restrict__ targ,
                                                   uint32_t* __restrict__ ws) {
    const int wid = (blockIdx.x << 2) + (threadIdx.x >> 6);   // strip id
    const int b = wid / (H / RPW);
    const int s0 = (wid - b * (H / RPW)) * RPW;               // first row (multiple of 8)
    const int l = threadIdx.x & 63;
    const int col = l << 3;
    const float sp = ((const float*)(ws + SH_OFF))[b];
    const float st = ((const float*)(ws + SH_OFF))[B + b];
    const float rp = ((const float*)(ws + RS_OFF))[b];
    const float rt = ((const float*)(ws + RS_OFF))[B + b];
    const float thr = ((const float*)(ws + THR_OFF))[b];
    const float* Pp = pred + (size_t)b * NPX;
    const float* Tp = targ + (size_t)b * NPX;

    const bool g1 = s0 >= 1, g2 = s0 >= 2, g4 = s0 >= 4, g8 = s0 >= 8;
    // ring[prv]=row i-1, ring[cur]=row i-2 when processing iteration it (cur=it&1)
    float rT[2][8], rPN[2][8];
    {
        const int roA = (g1 ? (s0 - 1) : s0) * W + col;
        const int roB = (g2 ? (s0 - 2) : s0) * W + col;
        float4 a0 = *(const float4*)(Tp + roA), a1 = *(const float4*)(Tp + roA + 4);
        float4 b0 = *(const float4*)(Pp + roA), b1 = *(const float4*)(Pp + roA + 4);
        float4 c0 = *(const float4*)(Tp + roB), c1 = *(const float4*)(Tp + roB + 4);
        float4 d0 = *(const float4*)(Pp + roB), d1 = *(const float4*)(Pp + roB + 4);
        float ta[8] = {a0.x,a0.y,a0.z,a0.w,a1.x,a1.y,a1.z,a1.w};
        float pa[8] = {b0.x,b0.y,b0.z,b0.w,b1.x,b1.y,b1.z,b1.w};
        float tc[8] = {c0.x,c0.y,c0.z,c0.w,c1.x,c1.y,c1.z,c1.w};
        float pc[8] = {d0.x,d0.y,d0.z,d0.w,d1.x,d1.y,d1.z,d1.w};
        #pragma unroll
        for (int k = 0; k < 8; k++) {
            rT[1][k] = ta[k]; rPN[1][k] = (pa[k] - sp) * rp;
            rT[0][k] = tc[k]; rPN[0][k] = (pc[k] - sp) * rp;
        }
    }

    float tl = 0.f, gl0 = 0.f, gl1 = 0.f, gl2 = 0.f, gl3 = 0.f;
    uint32_t mc = 0;

    #pragma unroll
    for (int it = 0; it < RPW; ++it) {
        const int ro = (s0 + it) * W + col;
        const int cur = it & 1, prv = cur ^ 1;
        float4 a0 = *(const float4*)(Tp + ro), a1 = *(const float4*)(Tp + ro + 4);
        float4 b0 = *(const float4*)(Pp + ro), b1 = *(const float4*)(Pp + ro + 4);
        float t[8] = {a0.x,a0.y,a0.z,a0.w,a1.x,a1.y,a1.z,a1.w};
        float p[8] = {b0.x,b0.y,b0.z,b0.w,b1.x,b1.y,b1.z,b1.w};
        // scale-2/3 boundary rows (L1/L2-warm; tiny scalar loads, static per it)
        float t4a = 0.f, t4b = 0.f, p4a = 0.f, p4b = 0.f, t8a = 0.f, p8a = 0.f;
        if (it == 0) {
            const int ro4 = g4 ? ro - 4 * W : ro;
            t4a = Tp[ro4]; t4b = Tp[ro4 + 4]; p4a = Pp[ro4]; p4b = Pp[ro4 + 4];
            const int ro8 = g8 ? ro - 8 * W : ro;
            t8a = Tp[ro8]; p8a = Pp[ro8];
        }
        if (it == 4) {
            const int ro4 = ro - 4 * W;
            t4a = Tp[ro4]; t4b = Tp[ro4 + 4]; p4a = Pp[ro4]; p4b = Pp[ro4 + 4];
        }
        float pn[8]; bool m[8];
        #pragma unroll
        for (int k = 0; k < 8; k++) { pn[k] = (p[k] - sp) * rp; m[k] = t[k] > st; }

        #pragma unroll
        for (int k = 0; k < 8; k++) {
            if (m[k]) {
                float tn = (t[k] - st) * rt;
                float r = fabsf(pn[k] - tn);
                if (r <= thr) tl += r;
            }
        }
        float t7p = __shfl_up(t[7], 1), pn7p = __shfl_up(pn[7], 1);
        // scale 0 horizontal
        if (l > 0 && m[0] && t7p > st) gl0 += fabsf(pn[0] - pn7p);
        #pragma unroll
        for (int k = 1; k < 8; k++) if (m[k] && m[k - 1]) gl0 += fabsf(pn[k] - pn[k - 1]);
        // scale 0 vertical (row i-1 from ring)
        if (it > 0 || g1) {
            #pragma unroll
            for (int k = 0; k < 8; k++)
                if (m[k] && rT[prv][k] > st) gl0 += fabsf(pn[k] - rPN[prv][k]);
        }
        if ((it & 1) == 0) {   // scale 1 (step 2); i parity == it parity (s0 % 8 == 0)
            float t6p = __shfl_up(t[6], 1), pn6p = __shfl_up(pn[6], 1);
            mc += (uint32_t)m[0] + m[2] + m[4] + m[6];
            if (l > 0 && m[0] && t6p > st) gl1 += fabsf(pn[0] - pn6p);
            if (m[2] && m[0]) gl1 += fabsf(pn[2] - pn[0]);
            if (m[4] && m[2]) gl1 += fabsf(pn[4] - pn[2]);
            if (m[6] && m[4]) gl1 += fabsf(pn[6] - pn[4]);
            if (it >= 2 || g2) {   // row i-2 from ring[cur]
                if (m[0] && rT[cur][0] > st) gl1 += fabsf(pn[0] - rPN[cur][0]);
                if (m[2] && rT[cur][2] > st) gl1 += fabsf(pn[2] - rPN[cur][2]);
                if (m[4] && rT[cur][4] > st) gl1 += fabsf(pn[4] - rPN[cur][4]);
                if (m[6] && rT[cur][6] > st) gl1 += fabsf(pn[6] - rPN[cur][6]);
            }
            if ((it & 3) == 0) {   // scale 2 (step 4)
                float t4p = __shfl_up(t[4], 1), pn4p = __shfl_up(pn[4], 1);
                mc += ((uint32_t)m[0] + m[4]) << 11;
                if (l > 0 && m[0] && t4p > st) gl2 += fabsf(pn[0] - pn4p);
                if (m[4] && m[0]) gl2 += fabsf(pn[4] - pn[0]);
                if (it == 4 || g4) {
                    if (m[0] && t4a > st) gl2 += fabsf(pn[0] - (p4a - sp) * rp);
                    if (m[4] && t4b > st) gl2 += fabsf(pn[4] - (p4b - sp) * rp);
                }
                if (it == 0) {     // scale 3 (step 8): only row s0 in strip
                    float t0p = __shfl_up(t[0], 1), pn0p = __shfl_up(pn[0], 1);
                    mc += ((uint32_t)m[0]) << 22;
                    if (l > 0 && m[0] && t0p > st) gl3 += fabsf(pn[0] - pn0p);
                    if (g8 && m[0] && t8a > st) gl3 += fabsf(pn[0] - (p8a - sp) * rp);
                }
            }
        }
        // rotate ring: current row becomes history
        #pragma unroll
        for (int k = 0; k < 8; k++) { rT[cur][k] = t[k]; rPN[cur][k] = pn[k]; }
    }

    for (int off = 32; off; off >>= 1) {
        tl  += __shfl_down(tl, off, 64);
        gl0 += __shfl_down(gl0, off, 64);
        gl1 += __shfl_down(gl1, off, 64);
        gl2 += __shfl_down(gl2, off, 64);
        gl3 += __shfl_down(gl3, off, 64);
        mc  += __shfl_down(mc, off, 64);
    }
    if (l == 0) {
        float* gs = (float*)(ws + GS_OFF);
        atomicAdd(((float*)(ws + TS_OFF)) + b, tl);
        atomicAdd(gs + b, gl0);
        atomicAdd(gs + B + b, gl1);
        atomicAdd(gs + 2 * B + b, gl2);
        atomicAdd(gs + 3 * B + b, gl3);
        atomicAdd(ws + MS_OFF + b, mc & 0x7FFu);
        atomicAdd(ws + MS_OFF + B + b, (mc >> 11) & 0x7FFu);
        atomicAdd(ws + MS_OFF + 2 * B + b, mc >> 22);
    }
}

// ---------------- finalize ----------------
__global__ void finalize_kernel(const uint32_t* __restrict__ ws, float* __restrict__ out) {
    const int b = threadIdx.x;
    float v = 0.f;
    if (b < B) {
        float c2 = (float)ws[C2_OFF + b];
        const float* tsum = (const float*)(ws + TS_OFF);
        const float* gsum = (const float*)(ws + GS_OFF);
        float tm = (c2 > 0.f) ? tsum[b] / (2.f * c2) : 0.f;
        float g = (c2 > 0.f) ? gsum[b] / c2 : 0.f;
        for (int z = 0; z < 3; z++) {
            float ms = (float)ws[MS_OFF + z * B + b];
            g += (ms > 0.f) ? gsum[(1 + z) * B + b] / ms : 0.f;
        }
        v = tm + 0.5f * g;
    }
    for (int off = 32; off; off >>= 1) v += __shfl_down(v, off, 64);
    if (b == 0) out[0] = v * (1.f / 64.f);
}

extern "C" void kernel_launch(void* const* d_in, const int* in_sizes, int n_in,
                              void* d_out, int out_size, void* d_ws, size_t ws_size,
                              hipStream_t stream) {
    const float* pred = (const float*)d_in[0];
    const float* targ = (const float*)d_in[1];
    float* out = (float*)d_out;
    uint32_t* ws = (uint32_t*)d_ws;

    hipMemsetAsync(ws, 0, (size_t)ZERO_U32 * 4, stream);

    dim3 hb(256), hg(32, B);   // 2048 blocks -> 8 blocks/CU, 32 waves/CU
    hist1_kernel<<<hg, hb, 0, stream>>>(pred, targ, ws);
    select_kernel<1><<<dim3(B, 2), 256, 0, stream>>>(ws);

    hist2_kernel<<<hg, hb, 0, stream>>>(pred, targ, ws);
    select_kernel<2><<<dim3(B, 2), 256, 0, stream>>>(ws);

    hist3_kernel<<<hg, hb, 0, stream>>>(pred, targ, ws);
    select3_kernel<<<dim3(B, 2), 256, 0, stream>>>(ws);

    param_kernel<<<1, 64, 0, stream>>>(pred, targ, ws);
    loss_kernel<<<dim3(B * (H / RPW) / 4), 256, 0, stream>>>(pred, targ, ws);
    finalize_kernel<<<1, 64, 0, stream>>>(ws, out);
}